// Round 1
// baseline (97.724 us; speedup 1.0000x reference)
//
#include <hip/hip_runtime.h>

// Precompute per-batch rotation table: tab[b] = (cos(theta), sin(theta), cos(phi), sin(phi))
__global__ void rot_precompute(const float* __restrict__ theta,
                               const float* __restrict__ phi,
                               float4* __restrict__ tab, int B) {
    int b = threadIdx.x;
    if (b < B) {
        float st, ct, sp, cp;
        sincosf(theta[b], &st, &ct);
        sincosf(phi[b], &sp, &cp);
        float4 r;
        r.x = ct; r.y = st; r.z = cp; r.w = sp;
        tab[b] = r;
    }
}

// Apply the two 2x2 rotations to each aligned float4 block.
// Grid: x = position within batch (in float4 units), y = batch index.
__global__ void rot_apply(const float4* __restrict__ in,
                          float4* __restrict__ out,
                          const float4* __restrict__ tab,
                          int per4) {
    int i = blockIdx.x * blockDim.x + threadIdx.x;
    if (i >= per4) return;
    long long idx = (long long)blockIdx.y * per4 + i;

    float4 t = tab[blockIdx.y];   // wave-uniform -> broadcast, L2-hit
    float4 v = in[idx];
    float4 o;
    o.x =  v.x * t.x + v.y * t.y;   // x0*ct + x1*st
    o.y = -v.x * t.y + v.y * t.x;   // -x0*st + x1*ct
    o.z =  v.z * t.z + v.w * t.w;   // x2*cp + x3*sp
    o.w = -v.z * t.w + v.w * t.z;   // -x2*sp + x3*cp
    out[idx] = o;
}

extern "C" void kernel_launch(void* const* d_in, const int* in_sizes, int n_in,
                              void* d_out, int out_size, void* d_ws, size_t ws_size,
                              hipStream_t stream) {
    const float* emb   = (const float*)d_in[0];
    const float* theta = (const float*)d_in[1];
    const float* phi   = (const float*)d_in[2];
    float* out = (float*)d_out;

    int B = in_sizes[1];                       // theta has B elements
    long long total = (long long)in_sizes[0];  // B*N*D
    long long per_batch = total / B;           // N*D
    int per4 = (int)(per_batch / 4);           // float4 blocks per batch

    float4* tab = (float4*)d_ws;

    rot_precompute<<<1, 64, 0, stream>>>(theta, phi, tab, B);

    const int threads = 256;
    int blocksX = (per4 + threads - 1) / threads;
    dim3 grid(blocksX, B);
    rot_apply<<<grid, threads, 0, stream>>>((const float4*)emb, (float4*)out, tab, per4);
}